// Round 14
// baseline (378.026 us; speedup 1.0000x reference)
//
#include <hip/hip_runtime.h>
#include <hip/hip_bf16.h>

// ---------------- types & helpers ----------------
typedef float f32x4 __attribute__((ext_vector_type(4)));
typedef short bf16x8 __attribute__((ext_vector_type(8)));

#define M_NT 16     // meta[16]     number of m-tiles
#define M_OFF 17    // meta[17..24] 128-aligned segment offsets
#define M_TBL 32    // meta[32..]   tile table: int4 {expert, base, valid, 0}
#define MAX_TILES 264   // 128-row tiles: <= 256 + 8
#define NCHUNK 1024     // router blocks; 16 tokens per chunk

__device__ __forceinline__ void gload16(const void* g, void* l) {
  __builtin_amdgcn_global_load_lds(
      (const __attribute__((address_space(1))) void*)g,
      (__attribute__((address_space(3))) void*)l, 16, 0, 0);
}

__device__ __forceinline__ float bf2f(unsigned short u) {
  union { unsigned int i; float f; } v; v.i = ((unsigned int)u) << 16; return v.f;
}
__device__ __forceinline__ unsigned short f2bf(float f) {
  __hip_bfloat16 h = __float2bfloat16(f);
  return __builtin_bit_cast(unsigned short, h);
}

#define CBAR() do { asm volatile("" ::: "memory"); __builtin_amdgcn_s_barrier(); asm volatile("" ::: "memory"); } while (0)
#define VMC4() asm volatile("s_waitcnt vmcnt(4)" ::: "memory")
#define VMC0() asm volatile("s_waitcnt vmcnt(0)" ::: "memory")

// ---------------- merged prep: router [0,1024) | We^T [1024,17408) | Wc^T [17408,19456) ----------------
__global__ __launch_bounds__(256) void prep_kernel(
    const float* __restrict__ x, const float* __restrict__ Wr,
    const float* __restrict__ br, unsigned short* __restrict__ xbf,
    float* __restrict__ scores, int* __restrict__ idx,
    int* __restrict__ blk_hist,
    const float* __restrict__ We, unsigned short* __restrict__ WeT,
    const float* __restrict__ Wc, unsigned short* __restrict__ WcT) {
  __shared__ float tile[32][33];
  __shared__ int cnt[8];
  int blk = blockIdx.x;
  int tid = threadIdx.x;
  if (blk < NCHUNK) {
    // ======== router: fp32 logits, softmax, top-2, fused x->bf16 ========
    int lane = tid & 63, w = tid >> 6;
    if (tid < 8) cnt[tid] = 0;
    __syncthreads();
    int t0 = blk * 16 + w * 4;
    const float* xr = x + (size_t)t0 * 2048;
    unsigned short* xo = xbf + (size_t)t0 * 2048;
    float acc[4][8] = {};
#pragma unroll
    for (int j = 0; j < 8; ++j) {
      int h0 = j * 256 + lane * 4;
      float4 xv[4];
#pragma unroll
      for (int t = 0; t < 4; ++t) xv[t] = *(const float4*)(xr + (size_t)t * 2048 + h0);
#pragma unroll
      for (int t = 0; t < 4; ++t) {
        ushort4 p;
        p.x = f2bf(xv[t].x); p.y = f2bf(xv[t].y);
        p.z = f2bf(xv[t].z); p.w = f2bf(xv[t].w);
        *(ushort4*)(xo + (size_t)t * 2048 + h0) = p;
      }
      const float4* wp = (const float4*)(Wr + (size_t)h0 * 8);
#pragma unroll
      for (int c = 0; c < 4; ++c) {
        float4 w0 = wp[2 * c], w1 = wp[2 * c + 1];
        float xc0 = (c == 0) ? xv[0].x : (c == 1) ? xv[0].y : (c == 2) ? xv[0].z : xv[0].w;
        float xc1 = (c == 0) ? xv[1].x : (c == 1) ? xv[1].y : (c == 2) ? xv[1].z : xv[1].w;
        float xc2 = (c == 0) ? xv[2].x : (c == 1) ? xv[2].y : (c == 2) ? xv[2].z : xv[2].w;
        float xc3 = (c == 0) ? xv[3].x : (c == 1) ? xv[3].y : (c == 2) ? xv[3].z : xv[3].w;
        acc[0][0] += xc0 * w0.x; acc[0][1] += xc0 * w0.y; acc[0][2] += xc0 * w0.z; acc[0][3] += xc0 * w0.w;
        acc[0][4] += xc0 * w1.x; acc[0][5] += xc0 * w1.y; acc[0][6] += xc0 * w1.z; acc[0][7] += xc0 * w1.w;
        acc[1][0] += xc1 * w0.x; acc[1][1] += xc1 * w0.y; acc[1][2] += xc1 * w0.z; acc[1][3] += xc1 * w0.w;
        acc[1][4] += xc1 * w1.x; acc[1][5] += xc1 * w1.y; acc[1][6] += xc1 * w1.z; acc[1][7] += xc1 * w1.w;
        acc[2][0] += xc2 * w0.x; acc[2][1] += xc2 * w0.y; acc[2][2] += xc2 * w0.z; acc[2][3] += xc2 * w0.w;
        acc[2][4] += xc2 * w1.x; acc[2][5] += xc2 * w1.y; acc[2][6] += xc2 * w1.z; acc[2][7] += xc2 * w1.w;
        acc[3][0] += xc3 * w0.x; acc[3][1] += xc3 * w0.y; acc[3][2] += xc3 * w0.z; acc[3][3] += xc3 * w0.w;
        acc[3][4] += xc3 * w1.x; acc[3][5] += xc3 * w1.y; acc[3][6] += xc3 * w1.z; acc[3][7] += xc3 * w1.w;
      }
    }
#pragma unroll
    for (int t = 0; t < 4; ++t)
#pragma unroll
      for (int e = 0; e < 8; ++e)
#pragma unroll
        for (int off = 32; off > 0; off >>= 1)
          acc[t][e] += __shfl_xor(acc[t][e], off);
    if (lane < 4) {
      int t = t0 + lane;
      float l[8];
#pragma unroll
      for (int e = 0; e < 8; ++e) {
        float v = (lane == 0) ? acc[0][e] : (lane == 1) ? acc[1][e]
                : (lane == 2) ? acc[2][e] : acc[3][e];
        l[e] = v + br[e];
      }
      float mx = l[0];
#pragma unroll
      for (int e = 1; e < 8; ++e) mx = fmaxf(mx, l[e]);
      float se = 0.f;
#pragma unroll
      for (int e = 0; e < 8; ++e) se += __expf(l[e] - mx);
      float inv = 1.f / se;
      int e1 = 0; float b1 = l[0];
#pragma unroll
      for (int e = 1; e < 8; ++e) if (l[e] > b1) { b1 = l[e]; e1 = e; }
      int e2 = -1; float b2 = -1e30f;
#pragma unroll
      for (int e = 0; e < 8; ++e) if (e != e1 && l[e] > b2) { b2 = l[e]; e2 = e; }
      idx[2 * t] = e1; idx[2 * t + 1] = e2;
      scores[2 * t] = __expf(b1 - mx) * inv;
      scores[2 * t + 1] = __expf(b2 - mx) * inv;
      atomicAdd(&cnt[e1], 1);   // LDS atomics only
      atomicAdd(&cnt[e2], 1);
    }
    __syncthreads();
    if (tid < 8) blk_hist[blk * 8 + tid] = cnt[tid];
  } else if (blk < NCHUNK + 16384) {
    // ======== We transpose: fp32 [8][2048][1024] -> bf16 [8][1024][2048] ========
    int i2 = blk - NCHUNK;
    int b = i2 >> 11, rem = i2 & 2047;
    int r0 = (rem >> 5) * 32, c0 = (rem & 31) * 32;
    const float* src = We + (size_t)b * 2048 * 1024;
    unsigned short* dst = WeT + (size_t)b * 2048 * 1024;
    int tx = tid & 31, ty = tid >> 5;
#pragma unroll
    for (int i = 0; i < 32; i += 8)
      tile[ty + i][tx] = src[(size_t)(r0 + ty + i) * 1024 + c0 + tx];
    __syncthreads();
#pragma unroll
    for (int i = 0; i < 32; i += 8)
      dst[(size_t)(c0 + ty + i) * 2048 + r0 + tx] = f2bf(tile[tx][ty + i]);
  } else {
    // ======== Wc transpose: fp32 [1024][2048] -> bf16 [2048][1024] ========
    int i2 = blk - NCHUNK - 16384;
    int r0 = (i2 >> 6) * 32, c0 = (i2 & 63) * 32;
    int tx = tid & 31, ty = tid >> 5;
#pragma unroll
    for (int i = 0; i < 32; i += 8)
      tile[ty + i][tx] = Wc[(size_t)(r0 + ty + i) * 2048 + c0 + tx];
    __syncthreads();
#pragma unroll
    for (int i = 0; i < 32; i += 8)
      WcT[(size_t)(c0 + ty + i) * 1024 + r0 + tx] = f2bf(tile[tx][ty + i]);
  }
}

// ---------------- scan: parallel prefix over chunk histograms (128-row tiles) ----------------
__global__ __launch_bounds__(512) void scan_kernel(
    const int* __restrict__ blk_hist, int* __restrict__ chunk_base,
    int* __restrict__ meta, int* __restrict__ rowlist) {
  __shared__ int stot[8], soff[8], stbase[8];
  int tid = threadIdx.x, lane = tid & 63, e = tid >> 6;
  int running = 0;
  for (int g = 0; g < NCHUNK / 64; ++g) {
    int c = g * 64 + lane;
    int v = blk_hist[c * 8 + e];
    int orig = v;
#pragma unroll
    for (int off = 1; off < 64; off <<= 1) {
      int n = __shfl_up(v, off);
      if (lane >= off) v += n;
    }
    chunk_base[c * 8 + e] = running + v - orig;
    running += __shfl(v, 63);
  }
  if (lane == 0) stot[e] = running;
  __syncthreads();
  if (tid == 0) {
    int off = 0, nt = 0;
    for (int ee = 0; ee < 8; ++ee) {
      meta[M_OFF + ee] = off; soff[ee] = off;
      int tiles = (stot[ee] + 127) >> 7;
      stbase[ee] = nt;
      nt += tiles;
      off += tiles << 7;
    }
    meta[M_NT] = nt;
  }
  __syncthreads();
  int4* tbl = (int4*)(meta + M_TBL);
  for (int ee = 0; ee < 8; ++ee) {
    int c = stot[ee], tiles = (c + 127) >> 7;
    for (int t = tid; t < tiles; t += 512)
      tbl[stbase[ee] + t] = make_int4(ee, soff[ee] + t * 128, min(128, c - t * 128), 0);
    int end = tiles << 7;
    for (int i = c + tid; i < end; i += 512) rowlist[soff[ee] + i] = 0;
  }
}

// ---------------- scatter: ballot-ranked, zero atomics ----------------
__global__ void scatter_kernel(const int* __restrict__ idx,
                               const int* __restrict__ chunk_base,
                               const int* __restrict__ meta,
                               int* __restrict__ rowlist) {
  int c = blockIdx.x, lane = threadIdx.x;
  int entry = c * 32 + lane;
  int e = (lane < 32) ? idx[entry] : -1;
#pragma unroll
  for (int ee = 0; ee < 8; ++ee) {
    unsigned long long m = __ballot(e == ee);
    if (e == ee) {
      int rank = __popcll(m & ((1ull << lane) - 1));
      rowlist[meta[M_OFF + ee] + chunk_base[c * 8 + ee] + rank] = entry;
    }
  }
}

// ============ 128x128 GEMM, BK=32, 3-buffer rotation, ONE barrier/K-tile ============
// 256 thr = 4 waves (2M x 2N); per-wave out 64x64 (acc 4x4 f32x4).
// LDS 48KiB: buf k at k*16384, each {A 8KB, B 8KB}; 3 blocks/CU.
// Iter t: [stage tile t+2 -> buf (t+2)%3] ; read buf t%3 ; MFMA ; vmcnt(4) ; barrier.
// Safety: buf (t+2)%3 last read at iter t-1, separated by t-1's barrier (WAR ok);
// vmcnt(4) retires iter t-1's stage so buf (t+1)%3 is resident for t+1 (FIFO ok).
// Swizzle sigma(row) = (row>>1)&3 (verified 2-way == free).

#define RD_FRAGS(BUFB) do { \
  _Pragma("unroll") for (int m_ = 0; m_ < 4; ++m_) \
    av[m_] = *(const bf16x8*)(aP + (BUFB) + m_ * 1024); \
  _Pragma("unroll") for (int n_ = 0; n_ < 4; ++n_) \
    bv[n_] = *(const bf16x8*)(bP + (BUFB) + n_ * 1024); \
} while (0)

#define MFMA16() do { \
  __builtin_amdgcn_s_setprio(1); \
  _Pragma("unroll") for (int m_ = 0; m_ < 4; ++m_) \
  _Pragma("unroll") for (int n_ = 0; n_ < 4; ++n_) \
    acc[m_][n_] = __builtin_amdgcn_mfma_f32_16x16x32_bf16(av[m_], bv[n_], acc[m_][n_], 0, 0, 0); \
  __builtin_amdgcn_s_setprio(0); \
} while (0)

#define STAGE(BUFB, KOFF) do { \
  gload16(pA0 + (KOFF), dA + (BUFB)); \
  gload16(pA1 + (KOFF), dA + (BUFB) + 4096); \
  gload16(pB0 + (KOFF), dB + (BUFB)); \
  gload16(pB1 + (KOFF), dB + (BUFB) + 4096); \
} while (0)

// one K-tile, single barrier
#define KT1(BUFR, BUFS, T, NTT) do { \
  if ((T) + 2 < (NTT)) STAGE(BUFS, ((T) + 2) * 64); \
  RD_FRAGS(BUFR); \
  MFMA16(); \
  if ((T) + 2 < (NTT)) { VMC4(); } else { VMC0(); } \
  CBAR(); \
} while (0)

// ---------------- expert GEMM: z[entry] = (x[t] @ We[e] + be[e]) * score ----------------
__global__ __launch_bounds__(256, 3) void expert_gemm(
    const unsigned short* __restrict__ xbf,   // [16384][2048] bf16
    const unsigned short* __restrict__ WeT,   // [8][1024][2048] bf16 (n-major)
    const float* __restrict__ be,             // [8][1024]
    const float* __restrict__ scores,         // [32768]
    const int* __restrict__ rowlist,
    const int* __restrict__ meta,
    unsigned short* __restrict__ z) {         // [32768][1024] bf16
  __shared__ char smem[49152];
  __shared__ int lrows[128];
  int nt = meta[M_NT];
  int flat = blockIdx.y * 8 + blockIdx.x;       // 2112 blocks
  int work = (flat & 7) * MAX_TILES + (flat >> 3);  // XCD-contiguous
  int tileid = work >> 3, nb = work & 7;
  if (tileid >= nt) return;
  int4 tt = ((const int4*)(meta + M_TBL))[tileid];
  int e = tt.x, base = tt.y, valid = tt.z;
  int n0 = nb * 128;
  int tid = threadIdx.x, lane = tid & 63, w = tid >> 6;
  if (tid < 128) lrows[tid] = rowlist[base + tid];
  __syncthreads();
  int wm = w >> 1, wn = w & 1;
  int fl = lane & 15, q = lane >> 4;
  int rA = tid >> 2;                            // 0..63; +64 for second load
  int sl = ((tid & 3) ^ ((rA >> 1) & 3)) * 16;  // inverse-swizzled 16B slot
  const char* pA0 = (const char*)xbf + (size_t)(lrows[rA] >> 1) * 4096 + sl;
  const char* pA1 = (const char*)xbf + (size_t)(lrows[rA + 64] >> 1) * 4096 + sl;
  const char* pB0 = (const char*)WeT + ((size_t)e * 1024 + n0 + rA) * 4096 + sl;
  const char* pB1 = (const char*)WeT + ((size_t)e * 1024 + n0 + rA + 64) * 4096 + sl;
  char* dA = smem + tid * 16;                   // linear dest (A region of buf)
  char* dB = smem + 8192 + tid * 16;
  int swz = ((fl >> 1) & 3) << 4;
  const char* aP = smem + (wm * 64 + fl) * 64 + ((q * 16) ^ swz);
  const char* bP = smem + 8192 + (wn * 64 + fl) * 64 + ((q * 16) ^ swz);
  // prologue: tiles 0 -> buf0, 1 -> buf1
  STAGE(0, 0); STAGE(16384, 64);
  VMC4(); CBAR();
  f32x4 acc[4][4] = {};
  bf16x8 av[4], bv[4];
  const int NT = 64;  // K=2048/32
  for (int t = 0; t < NT - 1; t += 3) {
    KT1(0,     32768, t,     NT);
    KT1(16384, 0,     t + 1, NT);
    KT1(32768, 16384, t + 2, NT);
  }
  KT1(0, 32768, NT - 1, NT);   // t=63: reads buf0 (63%3==0), no stage
  // epilogue
  float bev[4];
#pragma unroll
  for (int nc = 0; nc < 4; ++nc)
    bev[nc] = be[e * 1024 + n0 + wn * 64 + nc * 16 + fl];
#pragma unroll
  for (int mi = 0; mi < 4; ++mi) {
    int rowbase = wm * 64 + mi * 16 + q * 4;
#pragma unroll
    for (int r = 0; r < 4; ++r) {
      int row = rowbase + r;
      if (row < valid) {
        int entry = lrows[row];
        float s = scores[entry];
        unsigned short* zr = z + (size_t)entry * 1024 + n0 + wn * 64 + fl;
#pragma unroll
        for (int nc = 0; nc < 4; ++nc)
          zr[nc * 16] = f2bf((acc[mi][nc][r] + bev[nc]) * s);
      }
    }
  }
}

// ---------------- combine GEMM: out = y @ Wc + bc (fp32 out) ----------------
__global__ __launch_bounds__(256, 3) void combine_gemm(
    const unsigned short* __restrict__ y,    // [16384][1024] bf16
    const unsigned short* __restrict__ WcT,  // [2048][1024] bf16 (n-major)
    const float* __restrict__ bc,            // [2048]
    float* __restrict__ out) {               // [16384][2048] fp32
  __shared__ char smem[49152];
  int flat = blockIdx.y * 8 + blockIdx.x;     // 2048 blocks
  int work = (flat & 7) * 256 + (flat >> 3);
  int mt = work >> 4, nb = work & 15;
  int m0 = mt * 128, n0 = nb * 128;
  int tid = threadIdx.x, lane = tid & 63, w = tid >> 6;
  int wm = w >> 1, wn = w & 1;
  int fl = lane & 15, q = lane >> 4;
  int rA = tid >> 2;
  int sl = ((tid & 3) ^ ((rA >> 1) & 3)) * 16;
  const char* pA0 = (const char*)y + (size_t)(m0 + rA) * 2048 + sl;
  const char* pA1 = (const char*)y + (size_t)(m0 + rA + 64) * 2048 + sl;
  const char* pB0 = (const char*)WcT + (size_t)(n0 + rA) * 2048 + sl;
  const char* pB1 = (const char*)WcT + (size_t)(n0 + rA + 64) * 2048 + sl;
  char* dA = smem + tid * 16;
  char* dB = smem + 8192 + tid * 16;
  int swz = ((fl >> 1) & 3) << 4;
  const char* aP = smem + (wm * 64 + fl) * 64 + ((q * 16) ^ swz);
  const char* bP = smem + 8192 + (wn * 64 + fl) * 64 + ((q * 16) ^ swz);
  STAGE(0, 0); STAGE(16384, 64);
  VMC4(); CBAR();
  f32x4 acc[4][4] = {};
  bf16x8 av[4], bv[4];
  const int NT = 32;  // K=1024/32
  for (int t = 0; t < NT - 2; t += 3) {
    KT1(0,     32768, t,     NT);
    KT1(16384, 0,     t + 1, NT);
    KT1(32768, 16384, t + 2, NT);
  }
  KT1(0, 32768, NT - 2, NT);   // t=30: reads buf0 (30%3==0), no stage
  KT1(16384, 0, NT - 1, NT);   // t=31: reads buf1, no stage
  float bcv[4];
#pragma unroll
  for (int nc = 0; nc < 4; ++nc)
    bcv[nc] = bc[n0 + wn * 64 + nc * 16 + fl];
#pragma unroll
  for (int mi = 0; mi < 4; ++mi) {
    int rowbase = m0 + wm * 64 + mi * 16 + q * 4;
#pragma unroll
    for (int r = 0; r < 4; ++r) {
      float* orow = out + (size_t)(rowbase + r) * 2048 + n0 + wn * 64 + fl;
#pragma unroll
      for (int nc = 0; nc < 4; ++nc)
        orow[nc * 16] = acc[mi][nc][r] + bcv[nc];
    }
  }
}

// ---------------- weighted sum: y[t] = z[2t] + z[2t+1] (both pre-weighted) ----------------
__global__ void wsum_kernel(const unsigned short* __restrict__ z,
                            unsigned short* __restrict__ y) {
  size_t i = ((size_t)blockIdx.x * 256 + threadIdx.x) * 8;
  size_t t = i >> 10, d = i & 1023;
  int4 za = *(const int4*)(z + (t * 2) * 1024 + d);
  int4 zb = *(const int4*)(z + (t * 2 + 1) * 1024 + d);
  int4 r;
  const unsigned short* pa = (const unsigned short*)&za;
  const unsigned short* pb = (const unsigned short*)&zb;
  unsigned short* pr = (unsigned short*)&r;
#pragma unroll
  for (int j = 0; j < 8; ++j) pr[j] = f2bf(bf2f(pa[j]) + bf2f(pb[j]));
  *(int4*)(y + i) = r;
}

// ---------------- launch ----------------
extern "C" void kernel_launch(void* const* d_in, const int* in_sizes, int n_in,
                              void* d_out, int out_size, void* d_ws, size_t ws_size,
                              hipStream_t stream) {
  const float* x  = (const float*)d_in[0];
  const float* Wr = (const float*)d_in[1];
  const float* br = (const float*)d_in[2];
  const float* We = (const float*)d_in[3];
  const float* be = (const float*)d_in[4];
  const float* Wc = (const float*)d_in[5];
  const float* bc = (const float*)d_in[6];
  float* out = (float*)d_out;

  char* ws = (char*)d_ws;
  size_t o = 0;
  auto alloc = [&](size_t b) {
    char* p = ws + o;
    o = (o + b + 255) & ~(size_t)255;
    return p;
  };
  unsigned short* xbf = (unsigned short*)alloc(16384UL * 2048 * 2);
  unsigned short* WeT = (unsigned short*)alloc(8UL * 1024 * 2048 * 2);
  unsigned short* WcT = (unsigned short*)alloc(2048UL * 1024 * 2);
  unsigned short* z   = (unsigned short*)alloc(32768UL * 1024 * 2);
  unsigned short* yw  = (unsigned short*)alloc(16384UL * 1024 * 2);
  float* scores = (float*)alloc(32768UL * 4);
  int* idx      = (int*)alloc(32768UL * 4);
  int* rowlist  = (int*)alloc(36864UL * 4);
  int* meta     = (int*)alloc(8192);
  int* blk_hist = (int*)alloc(NCHUNK * 8 * 4);
  int* chunk_base = (int*)alloc(NCHUNK * 8 * 4);
  (void)ws_size; (void)in_sizes; (void)n_in; (void)out_size;

  hipLaunchKernelGGL(prep_kernel, dim3(NCHUNK + 16384 + 2048), dim3(256), 0, stream,
                     x, Wr, br, xbf, scores, idx, blk_hist, We, WeT, Wc, WcT);
  hipLaunchKernelGGL(scan_kernel, dim3(1), dim3(512), 0, stream, blk_hist, chunk_base, meta, rowlist);
  hipLaunchKernelGGL(scatter_kernel, dim3(NCHUNK), dim3(64), 0, stream, idx, chunk_base, meta, rowlist);
  hipLaunchKernelGGL(expert_gemm, dim3(8, MAX_TILES), dim3(256), 0, stream,
                     xbf, WeT, be, scores, rowlist, meta, z);
  hipLaunchKernelGGL(wsum_kernel, dim3(8192), dim3(256), 0, stream, z, yw);
  hipLaunchKernelGGL(combine_gemm, dim3(8, 256), dim3(256), 0, stream, yw, WcT, bc, out);
}

// Round 15
// 375.245 us; speedup vs baseline: 1.0074x; 1.0074x over previous
//
#include <hip/hip_runtime.h>
#include <hip/hip_bf16.h>

// ---------------- types & helpers ----------------
typedef float f32x4 __attribute__((ext_vector_type(4)));
typedef short bf16x8 __attribute__((ext_vector_type(8)));

#define M_NT 16     // meta[16]     number of m-tiles
#define M_OFF 17    // meta[17..24] 128-aligned segment offsets
#define M_TBL 32    // meta[32..]   tile table: int4 {expert, base, valid, 0}
#define MAX_TILES 264   // 128-row tiles: <= 256 + 8
#define NCHUNK 1024     // router blocks; 16 tokens per chunk

__device__ __forceinline__ void gload16(const void* g, void* l) {
  __builtin_amdgcn_global_load_lds(
      (const __attribute__((address_space(1))) void*)g,
      (__attribute__((address_space(3))) void*)l, 16, 0, 0);
}

__device__ __forceinline__ float bf2f(unsigned short u) {
  union { unsigned int i; float f; } v; v.i = ((unsigned int)u) << 16; return v.f;
}
__device__ __forceinline__ unsigned short f2bf(float f) {
  __hip_bfloat16 h = __float2bfloat16(f);
  return __builtin_bit_cast(unsigned short, h);
}

#define CBAR() do { asm volatile("" ::: "memory"); __builtin_amdgcn_s_barrier(); asm volatile("" ::: "memory"); } while (0)
#define VMC4() asm volatile("s_waitcnt vmcnt(4)" ::: "memory")
#define VMC0() asm volatile("s_waitcnt vmcnt(0)" ::: "memory")

// ---------------- merged prep: router [0,1024) | We^T [1024,17408) | Wc^T [17408,19456) ----------------
__global__ __launch_bounds__(256) void prep_kernel(
    const float* __restrict__ x, const float* __restrict__ Wr,
    const float* __restrict__ br, unsigned short* __restrict__ xbf,
    float* __restrict__ scores, int* __restrict__ idx,
    int* __restrict__ blk_hist,
    const float* __restrict__ We, unsigned short* __restrict__ WeT,
    const float* __restrict__ Wc, unsigned short* __restrict__ WcT) {
  __shared__ float tile[32][33];
  __shared__ int cnt[8];
  int blk = blockIdx.x;
  int tid = threadIdx.x;
  if (blk < NCHUNK) {
    // ======== router: fp32 logits, softmax, top-2, fused x->bf16 ========
    int lane = tid & 63, w = tid >> 6;
    if (tid < 8) cnt[tid] = 0;
    __syncthreads();
    int t0 = blk * 16 + w * 4;
    const float* xr = x + (size_t)t0 * 2048;
    unsigned short* xo = xbf + (size_t)t0 * 2048;
    float acc[4][8] = {};
#pragma unroll
    for (int j = 0; j < 8; ++j) {
      int h0 = j * 256 + lane * 4;
      float4 xv[4];
#pragma unroll
      for (int t = 0; t < 4; ++t) xv[t] = *(const float4*)(xr + (size_t)t * 2048 + h0);
#pragma unroll
      for (int t = 0; t < 4; ++t) {
        ushort4 p;
        p.x = f2bf(xv[t].x); p.y = f2bf(xv[t].y);
        p.z = f2bf(xv[t].z); p.w = f2bf(xv[t].w);
        *(ushort4*)(xo + (size_t)t * 2048 + h0) = p;
      }
      const float4* wp = (const float4*)(Wr + (size_t)h0 * 8);
#pragma unroll
      for (int c = 0; c < 4; ++c) {
        float4 w0 = wp[2 * c], w1 = wp[2 * c + 1];
        float xc0 = (c == 0) ? xv[0].x : (c == 1) ? xv[0].y : (c == 2) ? xv[0].z : xv[0].w;
        float xc1 = (c == 0) ? xv[1].x : (c == 1) ? xv[1].y : (c == 2) ? xv[1].z : xv[1].w;
        float xc2 = (c == 0) ? xv[2].x : (c == 1) ? xv[2].y : (c == 2) ? xv[2].z : xv[2].w;
        float xc3 = (c == 0) ? xv[3].x : (c == 1) ? xv[3].y : (c == 2) ? xv[3].z : xv[3].w;
        acc[0][0] += xc0 * w0.x; acc[0][1] += xc0 * w0.y; acc[0][2] += xc0 * w0.z; acc[0][3] += xc0 * w0.w;
        acc[0][4] += xc0 * w1.x; acc[0][5] += xc0 * w1.y; acc[0][6] += xc0 * w1.z; acc[0][7] += xc0 * w1.w;
        acc[1][0] += xc1 * w0.x; acc[1][1] += xc1 * w0.y; acc[1][2] += xc1 * w0.z; acc[1][3] += xc1 * w0.w;
        acc[1][4] += xc1 * w1.x; acc[1][5] += xc1 * w1.y; acc[1][6] += xc1 * w1.z; acc[1][7] += xc1 * w1.w;
        acc[2][0] += xc2 * w0.x; acc[2][1] += xc2 * w0.y; acc[2][2] += xc2 * w0.z; acc[2][3] += xc2 * w0.w;
        acc[2][4] += xc2 * w1.x; acc[2][5] += xc2 * w1.y; acc[2][6] += xc2 * w1.z; acc[2][7] += xc2 * w1.w;
        acc[3][0] += xc3 * w0.x; acc[3][1] += xc3 * w0.y; acc[3][2] += xc3 * w0.z; acc[3][3] += xc3 * w0.w;
        acc[3][4] += xc3 * w1.x; acc[3][5] += xc3 * w1.y; acc[3][6] += xc3 * w1.z; acc[3][7] += xc3 * w1.w;
      }
    }
#pragma unroll
    for (int t = 0; t < 4; ++t)
#pragma unroll
      for (int e = 0; e < 8; ++e)
#pragma unroll
        for (int off = 32; off > 0; off >>= 1)
          acc[t][e] += __shfl_xor(acc[t][e], off);
    if (lane < 4) {
      int t = t0 + lane;
      float l[8];
#pragma unroll
      for (int e = 0; e < 8; ++e) {
        float v = (lane == 0) ? acc[0][e] : (lane == 1) ? acc[1][e]
                : (lane == 2) ? acc[2][e] : acc[3][e];
        l[e] = v + br[e];
      }
      float mx = l[0];
#pragma unroll
      for (int e = 1; e < 8; ++e) mx = fmaxf(mx, l[e]);
      float se = 0.f;
#pragma unroll
      for (int e = 0; e < 8; ++e) se += __expf(l[e] - mx);
      float inv = 1.f / se;
      int e1 = 0; float b1 = l[0];
#pragma unroll
      for (int e = 1; e < 8; ++e) if (l[e] > b1) { b1 = l[e]; e1 = e; }
      int e2 = -1; float b2 = -1e30f;
#pragma unroll
      for (int e = 0; e < 8; ++e) if (e != e1 && l[e] > b2) { b2 = l[e]; e2 = e; }
      idx[2 * t] = e1; idx[2 * t + 1] = e2;
      scores[2 * t] = __expf(b1 - mx) * inv;
      scores[2 * t + 1] = __expf(b2 - mx) * inv;
      atomicAdd(&cnt[e1], 1);   // LDS atomics only
      atomicAdd(&cnt[e2], 1);
    }
    __syncthreads();
    if (tid < 8) blk_hist[blk * 8 + tid] = cnt[tid];
  } else if (blk < NCHUNK + 16384) {
    // ======== We transpose: fp32 [8][2048][1024] -> bf16 [8][1024][2048] ========
    int i2 = blk - NCHUNK;
    int b = i2 >> 11, rem = i2 & 2047;
    int r0 = (rem >> 5) * 32, c0 = (rem & 31) * 32;
    const float* src = We + (size_t)b * 2048 * 1024;
    unsigned short* dst = WeT + (size_t)b * 2048 * 1024;
    int tx = tid & 31, ty = tid >> 5;
#pragma unroll
    for (int i = 0; i < 32; i += 8)
      tile[ty + i][tx] = src[(size_t)(r0 + ty + i) * 1024 + c0 + tx];
    __syncthreads();
#pragma unroll
    for (int i = 0; i < 32; i += 8)
      dst[(size_t)(c0 + ty + i) * 2048 + r0 + tx] = f2bf(tile[tx][ty + i]);
  } else {
    // ======== Wc transpose: fp32 [1024][2048] -> bf16 [2048][1024] ========
    int i2 = blk - NCHUNK - 16384;
    int r0 = (i2 >> 6) * 32, c0 = (i2 & 63) * 32;
    int tx = tid & 31, ty = tid >> 5;
#pragma unroll
    for (int i = 0; i < 32; i += 8)
      tile[ty + i][tx] = Wc[(size_t)(r0 + ty + i) * 2048 + c0 + tx];
    __syncthreads();
#pragma unroll
    for (int i = 0; i < 32; i += 8)
      WcT[(size_t)(c0 + ty + i) * 1024 + r0 + tx] = f2bf(tile[tx][ty + i]);
  }
}

// ---------------- scan: parallel prefix over chunk histograms (128-row tiles) ----------------
__global__ __launch_bounds__(512) void scan_kernel(
    const int* __restrict__ blk_hist, int* __restrict__ chunk_base,
    int* __restrict__ meta, int* __restrict__ rowlist) {
  __shared__ int stot[8], soff[8], stbase[8];
  int tid = threadIdx.x, lane = tid & 63, e = tid >> 6;
  int running = 0;
  for (int g = 0; g < NCHUNK / 64; ++g) {
    int c = g * 64 + lane;
    int v = blk_hist[c * 8 + e];
    int orig = v;
#pragma unroll
    for (int off = 1; off < 64; off <<= 1) {
      int n = __shfl_up(v, off);
      if (lane >= off) v += n;
    }
    chunk_base[c * 8 + e] = running + v - orig;
    running += __shfl(v, 63);
  }
  if (lane == 0) stot[e] = running;
  __syncthreads();
  if (tid == 0) {
    int off = 0, nt = 0;
    for (int ee = 0; ee < 8; ++ee) {
      meta[M_OFF + ee] = off; soff[ee] = off;
      int tiles = (stot[ee] + 127) >> 7;
      stbase[ee] = nt;
      nt += tiles;
      off += tiles << 7;
    }
    meta[M_NT] = nt;
  }
  __syncthreads();
  int4* tbl = (int4*)(meta + M_TBL);
  for (int ee = 0; ee < 8; ++ee) {
    int c = stot[ee], tiles = (c + 127) >> 7;
    for (int t = tid; t < tiles; t += 512)
      tbl[stbase[ee] + t] = make_int4(ee, soff[ee] + t * 128, min(128, c - t * 128), 0);
    int end = tiles << 7;
    for (int i = c + tid; i < end; i += 512) rowlist[soff[ee] + i] = 0;
  }
}

// ---------------- scatter: ballot-ranked, zero atomics ----------------
__global__ void scatter_kernel(const int* __restrict__ idx,
                               const int* __restrict__ chunk_base,
                               const int* __restrict__ meta,
                               int* __restrict__ rowlist) {
  int c = blockIdx.x, lane = threadIdx.x;
  int entry = c * 32 + lane;
  int e = (lane < 32) ? idx[entry] : -1;
#pragma unroll
  for (int ee = 0; ee < 8; ++ee) {
    unsigned long long m = __ballot(e == ee);
    if (e == ee) {
      int rank = __popcll(m & ((1ull << lane) - 1));
      rowlist[meta[M_OFF + ee] + chunk_base[c * 8 + ee] + rank] = entry;
    }
  }
}

// ============ 128x128 GEMM, BK=32, 4 blocks/CU, 2-barrier/K-tile (best-measured R13) ============
// 256 thr = 4 waves (2M x 2N); per-wave out 64x64 (acc 4x4 f32x4).
// LDS 32KiB: buf0 {A 8KB @0, B 8KB @8192}, buf1 @16384.
// Swizzle sigma(row) = (row>>1)&3 (verified 2-way == free).
// setprio REMOVED per m190/T5 (null-to-negative in lockstep, non-phase-split schedules).

#define RD_FRAGS(BUFB) do { \
  _Pragma("unroll") for (int m_ = 0; m_ < 4; ++m_) \
    av[m_] = *(const bf16x8*)(aP + (BUFB) + m_ * 1024); \
  _Pragma("unroll") for (int n_ = 0; n_ < 4; ++n_) \
    bv[n_] = *(const bf16x8*)(bP + (BUFB) + n_ * 1024); \
} while (0)

#define MFMA16() do { \
  _Pragma("unroll") for (int m_ = 0; m_ < 4; ++m_) \
  _Pragma("unroll") for (int n_ = 0; n_ < 4; ++n_) \
    acc[m_][n_] = __builtin_amdgcn_mfma_f32_16x16x32_bf16(av[m_], bv[n_], acc[m_][n_], 0, 0, 0); \
} while (0)

#define STAGE(BUFB, KOFF) do { \
  gload16(pA0 + (KOFF), dA + (BUFB)); \
  gload16(pA1 + (KOFF), dA + (BUFB) + 4096); \
  gload16(pB0 + (KOFF), dB + (BUFB)); \
  gload16(pB1 + (KOFF), dB + (BUFB) + 4096); \
} while (0)

// ---------------- expert GEMM: z[entry] = (x[t] @ We[e] + be[e]) * score ----------------
__global__ __launch_bounds__(256, 4) void expert_gemm(
    const unsigned short* __restrict__ xbf,   // [16384][2048] bf16
    const unsigned short* __restrict__ WeT,   // [8][1024][2048] bf16 (n-major)
    const float* __restrict__ be,             // [8][1024]
    const float* __restrict__ scores,         // [32768]
    const int* __restrict__ rowlist,
    const int* __restrict__ meta,
    unsigned short* __restrict__ z) {         // [32768][1024] bf16
  __shared__ char smem[32768];
  __shared__ int lrows[128];
  int nt = meta[M_NT];
  int flat = blockIdx.y * 8 + blockIdx.x;       // 2112 blocks
  int work = (flat & 7) * MAX_TILES + (flat >> 3);  // XCD-contiguous
  int tileid = work >> 3, nb = work & 7;
  if (tileid >= nt) return;
  int4 tt = ((const int4*)(meta + M_TBL))[tileid];
  int e = tt.x, base = tt.y, valid = tt.z;
  int n0 = nb * 128;
  int tid = threadIdx.x, lane = tid & 63, w = tid >> 6;
  if (tid < 128) lrows[tid] = rowlist[base + tid];
  __syncthreads();
  int wm = w >> 1, wn = w & 1;
  int fl = lane & 15, q = lane >> 4;
  int rA = tid >> 2;                            // 0..63; +64 for second load
  int sl = ((tid & 3) ^ ((rA >> 1) & 3)) * 16;  // inverse-swizzled 16B slot
  const char* pA0 = (const char*)xbf + (size_t)(lrows[rA] >> 1) * 4096 + sl;
  const char* pA1 = (const char*)xbf + (size_t)(lrows[rA + 64] >> 1) * 4096 + sl;
  const char* pB0 = (const char*)WeT + ((size_t)e * 1024 + n0 + rA) * 4096 + sl;
  const char* pB1 = (const char*)WeT + ((size_t)e * 1024 + n0 + rA + 64) * 4096 + sl;
  char* dA = smem + tid * 16;                   // linear dest
  char* dB = smem + 8192 + tid * 16;
  int swz = ((fl >> 1) & 3) << 4;
  const char* aP = smem + (wm * 64 + fl) * 64 + ((q * 16) ^ swz);
  const char* bP = smem + 8192 + (wn * 64 + fl) * 64 + ((q * 16) ^ swz);
  STAGE(0, 0); STAGE(16384, 64);
  VMC4(); CBAR();
  f32x4 acc[4][4] = {};
  bf16x8 av[4], bv[4];
  const int NT = 64;  // K=2048/32
  for (int t2 = 0; t2 < NT; t2 += 2) {
    int koff = t2 * 64;
    RD_FRAGS(0);
    MFMA16();
    CBAR();
    if (t2 + 2 < NT) { STAGE(0, koff + 128); VMC4(); } else { VMC0(); }
    CBAR();
    RD_FRAGS(16384);
    MFMA16();
    CBAR();
    if (t2 + 3 < NT) { STAGE(16384, koff + 192); VMC4(); } else { VMC0(); }
    CBAR();
  }
  float bev[4];
#pragma unroll
  for (int nc = 0; nc < 4; ++nc)
    bev[nc] = be[e * 1024 + n0 + wn * 64 + nc * 16 + fl];
#pragma unroll
  for (int mi = 0; mi < 4; ++mi) {
    int rowbase = wm * 64 + mi * 16 + q * 4;
#pragma unroll
    for (int r = 0; r < 4; ++r) {
      int row = rowbase + r;
      if (row < valid) {
        int entry = lrows[row];
        float s = scores[entry];
        unsigned short* zr = z + (size_t)entry * 1024 + n0 + wn * 64 + fl;
#pragma unroll
        for (int nc = 0; nc < 4; ++nc)
          zr[nc * 16] = f2bf((acc[mi][nc][r] + bev[nc]) * s);
      }
    }
  }
}

// ---------------- combine GEMM: out = y @ Wc + bc (fp32 out) ----------------
__global__ __launch_bounds__(256, 4) void combine_gemm(
    const unsigned short* __restrict__ y,    // [16384][1024] bf16
    const unsigned short* __restrict__ WcT,  // [2048][1024] bf16 (n-major)
    const float* __restrict__ bc,            // [2048]
    float* __restrict__ out) {               // [16384][2048] fp32
  __shared__ char smem[32768];
  int flat = blockIdx.y * 8 + blockIdx.x;     // 2048 blocks
  int work = (flat & 7) * 256 + (flat >> 3);
  int mt = work >> 4, nb = work & 15;
  int m0 = mt * 128, n0 = nb * 128;
  int tid = threadIdx.x, lane = tid & 63, w = tid >> 6;
  int wm = w >> 1, wn = w & 1;
  int fl = lane & 15, q = lane >> 4;
  int rA = tid >> 2;
  int sl = ((tid & 3) ^ ((rA >> 1) & 3)) * 16;
  const char* pA0 = (const char*)y + (size_t)(m0 + rA) * 2048 + sl;
  const char* pA1 = (const char*)y + (size_t)(m0 + rA + 64) * 2048 + sl;
  const char* pB0 = (const char*)WcT + (size_t)(n0 + rA) * 2048 + sl;
  const char* pB1 = (const char*)WcT + (size_t)(n0 + rA + 64) * 2048 + sl;
  char* dA = smem + tid * 16;
  char* dB = smem + 8192 + tid * 16;
  int swz = ((fl >> 1) & 3) << 4;
  const char* aP = smem + (wm * 64 + fl) * 64 + ((q * 16) ^ swz);
  const char* bP = smem + 8192 + (wn * 64 + fl) * 64 + ((q * 16) ^ swz);
  STAGE(0, 0); STAGE(16384, 64);
  VMC4(); CBAR();
  f32x4 acc[4][4] = {};
  bf16x8 av[4], bv[4];
  const int NT = 32;  // K=1024/32
  for (int t2 = 0; t2 < NT; t2 += 2) {
    int koff = t2 * 64;
    RD_FRAGS(0);
    MFMA16();
    CBAR();
    if (t2 + 2 < NT) { STAGE(0, koff + 128); VMC4(); } else { VMC0(); }
    CBAR();
    RD_FRAGS(16384);
    MFMA16();
    CBAR();
    if (t2 + 3 < NT) { STAGE(16384, koff + 192); VMC4(); } else { VMC0(); }
    CBAR();
  }
  float bcv[4];
#pragma unroll
  for (int nc = 0; nc < 4; ++nc)
    bcv[nc] = bc[n0 + wn * 64 + nc * 16 + fl];
#pragma unroll
  for (int mi = 0; mi < 4; ++mi) {
    int rowbase = m0 + wm * 64 + mi * 16 + q * 4;
#pragma unroll
    for (int r = 0; r < 4; ++r) {
      float* orow = out + (size_t)(rowbase + r) * 2048 + n0 + wn * 64 + fl;
#pragma unroll
      for (int nc = 0; nc < 4; ++nc)
        orow[nc * 16] = acc[mi][nc][r] + bcv[nc];
    }
  }
}

// ---------------- weighted sum: y[t] = z[2t] + z[2t+1] (both pre-weighted) ----------------
__global__ void wsum_kernel(const unsigned short* __restrict__ z,
                            unsigned short* __restrict__ y) {
  size_t i = ((size_t)blockIdx.x * 256 + threadIdx.x) * 8;
  size_t t = i >> 10, d = i & 1023;
  int4 za = *(const int4*)(z + (t * 2) * 1024 + d);
  int4 zb = *(const int4*)(z + (t * 2 + 1) * 1024 + d);
  int4 r;
  const unsigned short* pa = (const unsigned short*)&za;
  const unsigned short* pb = (const unsigned short*)&zb;
  unsigned short* pr = (unsigned short*)&r;
#pragma unroll
  for (int j = 0; j < 8; ++j) pr[j] = f2bf(bf2f(pa[j]) + bf2f(pb[j]));
  *(int4*)(y + i) = r;
}

// ---------------- launch ----------------
extern "C" void kernel_launch(void* const* d_in, const int* in_sizes, int n_in,
                              void* d_out, int out_size, void* d_ws, size_t ws_size,
                              hipStream_t stream) {
  const float* x  = (const float*)d_in[0];
  const float* Wr = (const float*)d_in[1];
  const float* br = (const float*)d_in[2];
  const float* We = (const float*)d_in[3];
  const float* be = (const float*)d_in[4];
  const float* Wc = (const float*)d_in[5];
  const float* bc = (const float*)d_in[6];
  float* out = (float*)d_out;

  char* ws = (char*)d_ws;
  size_t o = 0;
  auto alloc = [&](size_t b) {
    char* p = ws + o;
    o = (o + b + 255) & ~(size_t)255;
    return p;
  };
  unsigned short* xbf = (unsigned short*)alloc(16384UL * 2048 * 2);
  unsigned short* WeT = (unsigned short*)alloc(8UL * 1024 * 2048 * 2);
  unsigned short* WcT = (unsigned short*)alloc(2048UL * 1024 * 2);
  unsigned short* z   = (unsigned short*)alloc(32768UL * 1024 * 2);
  unsigned short* yw  = (unsigned short*)alloc(16384UL * 1024 * 2);
  float* scores = (float*)alloc(32768UL * 4);
  int* idx      = (int*)alloc(32768UL * 4);
  int* rowlist  = (int*)alloc(36864UL * 4);
  int* meta     = (int*)alloc(8192);
  int* blk_hist = (int*)alloc(NCHUNK * 8 * 4);
  int* chunk_base = (int*)alloc(NCHUNK * 8 * 4);
  (void)ws_size; (void)in_sizes; (void)n_in; (void)out_size;

  hipLaunchKernelGGL(prep_kernel, dim3(NCHUNK + 16384 + 2048), dim3(256), 0, stream,
                     x, Wr, br, xbf, scores, idx, blk_hist, We, WeT, Wc, WcT);
  hipLaunchKernelGGL(scan_kernel, dim3(1), dim3(512), 0, stream, blk_hist, chunk_base, meta, rowlist);
  hipLaunchKernelGGL(scatter_kernel, dim3(NCHUNK), dim3(64), 0, stream, idx, chunk_base, meta, rowlist);
  hipLaunchKernelGGL(expert_gemm, dim3(8, MAX_TILES), dim3(256), 0, stream,
                     xbf, WeT, be, scores, rowlist, meta, z);
  hipLaunchKernelGGL(wsum_kernel, dim3(8192), dim3(256), 0, stream, z, yw);
  hipLaunchKernelGGL(combine_gemm, dim3(8, 256), dim3(256), 0, stream, yw, WcT, bc, out);
}